// Round 4
// baseline (7329.552 us; speedup 1.0000x reference)
//
#include <hip/hip_runtime.h>

// Problem: new_LSTM_30365418783418  (B=128, T=256, I=512, H=1024)
// R4 theory: inputs/outputs are FLOAT32 (per the reference; the "(bf16" in the
// harness label is a hardcoded f-string literal). Reading f32 as bf16 explains
// 3 rounds of NaN (~1/256 of f32 low-halves decode to bf16 NaN/Inf).
// Plan: convert x/x_d/weights f32->bf16 once into ws; MFMA bf16 compute with
// f32 accumulators/cell/biases; write f32 outputs.
//
// d_in: 0:x 1:x_d 2:hidden 3:cell | 4..9: Wii,Wif,Wig,Wio,Wid,Wro (H,I)
//       10..14: Whi,Whf,Whg,Who,Whd (H,H) | 15..20: bi,bf,bg,bo,bd,Wrb (H,)
// d_out: y(128,256,1024) ++ h_last(128,1024) ++ c_last(128,1024), float32.

using bf16x8 = __attribute__((ext_vector_type(8))) __bf16;
using f32x4  = __attribute__((ext_vector_type(4))) float;

#define MFMA16(a, b, c) __builtin_amdgcn_mfma_f32_16x16x32_bf16(a, b, c, 0, 0, 0)

static __device__ __forceinline__ float b2f(ushort u) {
  union { unsigned int i; float f; } v; v.i = ((unsigned int)u) << 16; return v.f;
}
static __device__ __forceinline__ ushort f2b(float f) {
  union { float f; unsigned int i; } v; v.f = f;
  unsigned int x = v.i;
  return (ushort)((x + 0x7fffu + ((x >> 16) & 1u)) >> 16);  // RNE
}
static __device__ __forceinline__ float sigm(float x) {
  return 1.0f / (1.0f + __expf(-x));
}
static __device__ __forceinline__ float tanhfast(float x) {
  float e = __expf(2.0f * x);          // tanh = 1 - 2/(e^{2x}+1); saturates
  return 1.0f - 2.0f / (e + 1.0f);
}

// ---------------------------------------------------------------------------
// f32 -> bf16 conversion, 4 elems/thread. n % 4 == 0.
// ---------------------------------------------------------------------------
__global__ __launch_bounds__(256) void cvt_kernel(const float* __restrict__ src,
                                                  ushort* __restrict__ dst, int n)
{
  int i = (blockIdx.x * 256 + threadIdx.x) * 4;
  if (i < n) {
    float4 v = *(const float4*)(src + i);
    ushort4 o;
    o.x = f2b(v.x); o.y = f2b(v.y); o.z = f2b(v.z); o.w = f2b(v.w);
    *(ushort4*)(dst + i) = o;
  }
}

// ---------------------------------------------------------------------------
// Generic 128x128 NT bf16 GEMM K-loop, plain-load LDS staging.
// ---------------------------------------------------------------------------
static __device__ __forceinline__ void gemm_kloop(
    const ushort* __restrict__ A, int lda,
    const ushort* __restrict__ Bw, int ldb, int K,
    ushort* As, ushort* Bs, f32x4 (&acc)[4][4])
{
  const int tid = threadIdx.x;
  const int l = tid & 63, w = tid >> 6;
  const int wm = (w >> 1) * 64, wn = (w & 1) * 64;
  const int lr = l & 15, quad = l >> 4;
  bf16x8* Asv = (bf16x8*)As;
  bf16x8* Bsv = (bf16x8*)Bs;
  for (int k0 = 0; k0 < K; k0 += 32) {
    __syncthreads();
#pragma unroll
    for (int it = 0; it < 2; ++it) {
      int c = it * 256 + tid;
      int row = c >> 2, seg = c & 3;
      Asv[c] = *(const bf16x8*)(A  + row * lda + k0 + seg * 8);
      Bsv[c] = *(const bf16x8*)(Bw + row * ldb + k0 + seg * 8);
    }
    __syncthreads();
    bf16x8 af[4], bfr[4];
#pragma unroll
    for (int i = 0; i < 4; ++i) af[i]  = Asv[(wm + i * 16 + lr) * 4 + quad];
#pragma unroll
    for (int j = 0; j < 4; ++j) bfr[j] = Bsv[(wn + j * 16 + lr) * 4 + quad];
#pragma unroll
    for (int i = 0; i < 4; ++i)
#pragma unroll
      for (int j = 0; j < 4; ++j)
        acc[i][j] = MFMA16(af[i], bfr[j], acc[i][j]);
  }
}

// ---------------------------------------------------------------------------
// Kernel 1 (per chunk): P[m'][g*1024+h] = bf16( A[b, t0+tt] . Wg[h] + bias )
// m' = b*chunk + tt. Grid (chunk, 40), 256 threads.
// ---------------------------------------------------------------------------
__global__ __launch_bounds__(256) void gemm_pre(
    const ushort* __restrict__ xb, const ushort* __restrict__ xdb,
    const ushort* __restrict__ Wb,      // 6x(1024x512) contiguous (Wii..Wid,Wro)
    const float* __restrict__ bias5, ushort* __restrict__ P,
    int t0, int lc)
{
  __shared__ __align__(16) ushort As[4096], Bs[4096];
  const int m0 = blockIdx.x * 128;
  const int n0 = blockIdx.y * 128;
  const int g = n0 >> 10;
  const ushort* A = (g == 4) ? xdb : xb;
  const ushort* Bw = Wb + g * 524288 + (n0 & 1023) * 512;
  const int cm1 = (1 << lc) - 1;

  const int tid = threadIdx.x;
  const int l = tid & 63, w = tid >> 6;
  const int wm = (w >> 1) * 64, wn = (w & 1) * 64;
  const int lr = l & 15, quad = l >> 4;
  f32x4 acc[4][4] = {};
  bf16x8* Asv = (bf16x8*)As;
  bf16x8* Bsv = (bf16x8*)Bs;

  for (int k0 = 0; k0 < 512; k0 += 32) {
    __syncthreads();
#pragma unroll
    for (int it = 0; it < 2; ++it) {
      int c = it * 256 + tid;
      int row = c >> 2, seg = c & 3;
      int gr = m0 + row;                              // m' row
      int arow = ((gr >> lc) << 8) + t0 + (gr & cm1); // b*T + t
      Asv[c] = *(const bf16x8*)(A  + arow * 512 + k0 + seg * 8);
      Bsv[c] = *(const bf16x8*)(Bw + row  * 512 + k0 + seg * 8);
    }
    __syncthreads();
    bf16x8 af[4], bfr[4];
#pragma unroll
    for (int i = 0; i < 4; ++i) af[i]  = Asv[(wm + i * 16 + lr) * 4 + quad];
#pragma unroll
    for (int j = 0; j < 4; ++j) bfr[j] = Bsv[(wn + j * 16 + lr) * 4 + quad];
#pragma unroll
    for (int i = 0; i < 4; ++i)
#pragma unroll
      for (int j = 0; j < 4; ++j)
        acc[i][j] = MFMA16(af[i], bfr[j], acc[i][j]);
  }

#pragma unroll
  for (int i = 0; i < 4; ++i)
#pragma unroll
    for (int j = 0; j < 4; ++j) {
      int row = m0 + wm + i * 16 + quad * 4;   // C/D: row = quad*4+reg (m89)
      int col = n0 + wn + j * 16 + lr;         //      col = lane&15
      float bias = bias5[col];
#pragma unroll
      for (int r = 0; r < 4; ++r)
        P[(row + r) * 5120 + col] = f2b(acc[i][j][r] + bias);
    }
}

// ---------------------------------------------------------------------------
// Kernel 2 (x256): one LSTM step. Grid (4,64) x 64 threads (1 wave/block).
// Rows m0..m0+31 x h-cols hc..hc+15, 5 gates fused, K=1024 direct global
// fragment loads (Whb L2-resident: 5x(1024x1024) contiguous).
// ---------------------------------------------------------------------------
__global__ __launch_bounds__(64) void lstm_step(
    const ushort* __restrict__ hprev, ushort* __restrict__ hnext,
    float* __restrict__ cbuf, const ushort* __restrict__ Whb,
    const ushort* __restrict__ P, ushort* __restrict__ hs,
    int t, int tloc, int lc)
{
  const int l = threadIdx.x;
  const int m0 = blockIdx.x * 32;
  const int hc = blockIdx.y * 16;
  const int lr = l & 15, quad = l >> 4;

  f32x4 acc[2][5] = {};
  const ushort* a0p = hprev + (m0 + lr) * 1024 + quad * 8;
  const ushort* a1p = a0p + 16 * 1024;
  const ushort* wp = Whb + (hc + lr) * 1024 + quad * 8;

#pragma unroll 2
  for (int k0 = 0; k0 < 1024; k0 += 32) {
    bf16x8 a0 = *(const bf16x8*)(a0p + k0);
    bf16x8 a1 = *(const bf16x8*)(a1p + k0);
    bf16x8 b0 = *(const bf16x8*)(wp + k0);
    bf16x8 b1 = *(const bf16x8*)(wp + 1048576 + k0);
    bf16x8 b2 = *(const bf16x8*)(wp + 2097152 + k0);
    bf16x8 b3 = *(const bf16x8*)(wp + 3145728 + k0);
    bf16x8 b4 = *(const bf16x8*)(wp + 4194304 + k0);
    acc[0][0] = MFMA16(a0, b0, acc[0][0]);
    acc[1][0] = MFMA16(a1, b0, acc[1][0]);
    acc[0][1] = MFMA16(a0, b1, acc[0][1]);
    acc[1][1] = MFMA16(a1, b1, acc[1][1]);
    acc[0][2] = MFMA16(a0, b2, acc[0][2]);
    acc[1][2] = MFMA16(a1, b2, acc[1][2]);
    acc[0][3] = MFMA16(a0, b3, acc[0][3]);
    acc[1][3] = MFMA16(a1, b3, acc[1][3]);
    acc[0][4] = MFMA16(a0, b4, acc[0][4]);
    acc[1][4] = MFMA16(a1, b4, acc[1][4]);
  }

  const int h = hc + lr;
#pragma unroll
  for (int i = 0; i < 2; ++i) {
#pragma unroll
    for (int r = 0; r < 4; ++r) {
      int b = m0 + i * 16 + quad * 4 + r;     // C/D row mapping (m89)
      int prow = ((b << lc) + tloc) * 5120;   // chunk-local P row
      float pi = b2f(P[prow + h])          + acc[i][0][r];
      float pf = b2f(P[prow + 1024 + h])   + acc[i][1][r];
      float pg = b2f(P[prow + 2048 + h])   + acc[i][2][r];
      float po = b2f(P[prow + 3072 + h])   + acc[i][3][r];
      float pd = b2f(P[prow + 4096 + h])   + acc[i][4][r];
      float ig = sigm(pi), fg = sigm(pf), gg = tanhfast(pg);
      float og = sigm(po), dg = sigm(pd);
      float cold = cbuf[b * 1024 + h];
      float cnew = fg * cold + ig * gg + dg;
      cbuf[b * 1024 + h] = cnew;
      ushort hb = f2b(og * tanhfast(cnew));
      hnext[b * 1024 + h] = hb;
      hs[(b * 256 + t) * 1024 + h] = hb;
    }
  }
}

// ---------------------------------------------------------------------------
// Kernel 3: y = tanh(x@Wro^T + hs@Who^T + Wrb), f32 out. Grid (256, 8).
// ---------------------------------------------------------------------------
__global__ __launch_bounds__(256) void gemm_post(
    const ushort* __restrict__ xb, const ushort* __restrict__ hs,
    const ushort* __restrict__ Wrob, const ushort* __restrict__ Whob,
    const float* __restrict__ Wrb, float* __restrict__ y)
{
  __shared__ __align__(16) ushort As[4096], Bs[4096];
  const int m0 = blockIdx.x * 128;
  const int n0 = blockIdx.y * 128;
  f32x4 acc[4][4] = {};
  gemm_kloop(xb + m0 * 512,  512,  Wrob + n0 * 512,  512,  512,  As, Bs, acc);
  gemm_kloop(hs + m0 * 1024, 1024, Whob + n0 * 1024, 1024, 1024, As, Bs, acc);

  const int tid = threadIdx.x;
  const int l = tid & 63, w = tid >> 6;
  const int wm = (w >> 1) * 64, wn = (w & 1) * 64;
  const int lr = l & 15, quad = l >> 4;
#pragma unroll
  for (int i = 0; i < 4; ++i)
#pragma unroll
    for (int j = 0; j < 4; ++j) {
      int row = m0 + wm + i * 16 + quad * 4;
      int col = n0 + wn + j * 16 + lr;
      float bias = Wrb[col];
#pragma unroll
      for (int r = 0; r < 4; ++r)
        y[(row + r) * 1024 + col] = tanhfast(acc[i][j][r] + bias);
    }
}

// ---------------------------------------------------------------------------
// finish: h_last (bf16->f32) and c_last (f32) into d_out tail.
// ---------------------------------------------------------------------------
__global__ __launch_bounds__(256) void finish_kernel(
    const ushort* __restrict__ hfin, const float* __restrict__ cbuf,
    float* __restrict__ out_tail)
{
  int i = blockIdx.x * 256 + threadIdx.x;
  if (i < 131072) {
    out_tail[i] = b2f(hfin[i]);
    out_tail[131072 + i] = cbuf[i];
  }
}

// ---------------------------------------------------------------------------
extern "C" void kernel_launch(void* const* d_in, const int* in_sizes, int n_in,
                              void* d_out, int out_size, void* d_ws, size_t ws_size,
                              hipStream_t stream)
{
  const float* x   = (const float*)d_in[0];
  const float* xd  = (const float*)d_in[1];
  const float* hid = (const float*)d_in[2];
  const float* cel = (const float*)d_in[3];
  // input weights converted into Wb block in this order: Wii,Wif,Wig,Wio,Wid,Wro
  const float* Win[6] = {(const float*)d_in[4], (const float*)d_in[5],
                         (const float*)d_in[6], (const float*)d_in[7],
                         (const float*)d_in[8], (const float*)d_in[9]};
  // recurrent weights: Whi,Whf,Whg,Who,Whd
  const float* Whn[5] = {(const float*)d_in[10], (const float*)d_in[11],
                         (const float*)d_in[12], (const float*)d_in[13],
                         (const float*)d_in[14]};
  const float* bia[5] = {(const float*)d_in[15], (const float*)d_in[16],
                         (const float*)d_in[17], (const float*)d_in[18],
                         (const float*)d_in[19]};
  const float* Wrb = (const float*)d_in[20];
  float* y = (float*)d_out;

  // ws carve (bytes):
  char* ws = (char*)d_ws;
  ushort* xb    = (ushort*)(ws);                  //  33,554,432
  ushort* xdb   = (ushort*)(ws + 33554432);       //  33,554,432
  ushort* Wb    = (ushort*)(ws + 67108864);       //   6,291,456 (6x 1024x512)
  ushort* Whb   = (ushort*)(ws + 73400320);       //  10,485,760 (5x 1024x1024)
  ushort* hs    = (ushort*)(ws + 83886080);       //  67,108,864
  ushort* h0    = (ushort*)(ws + 150994944);      //     262,144
  ushort* h1    = (ushort*)(ws + 151257088);      //     262,144
  float*  cbuf  = (float*) (ws + 151519232);      //     524,288
  float*  bias5 = (float*) (ws + 152043520);      //      20,480
  ushort* P     = (ushort*)(ws + 152064000);      // chunk*1,310,720

  // Largest pow2 chunk (divisor of 256) whose P fits; floor at 1.
  int chunk = 1;
  for (int c = 256; c >= 1; c >>= 1)
    if (152064000ull + (unsigned long long)c * 1310720ull <= (unsigned long long)ws_size) {
      chunk = c; break;
    }
  int lc = 31 - __builtin_clz((unsigned)chunk);

  // --- conversions f32 -> bf16 ---
  cvt_kernel<<<16384, 256, 0, stream>>>(x,  xb,  16777216);
  cvt_kernel<<<16384, 256, 0, stream>>>(xd, xdb, 16777216);
  for (int i = 0; i < 6; ++i)
    cvt_kernel<<<512, 256, 0, stream>>>(Win[i], Wb + i * 524288, 524288);
  for (int i = 0; i < 5; ++i)
    cvt_kernel<<<1024, 256, 0, stream>>>(Whn[i], Whb + i * 1048576, 1048576);
  cvt_kernel<<<128, 256, 0, stream>>>(hid, h0, 131072);
  hipMemcpyAsync(cbuf, cel, 131072 * 4, hipMemcpyDeviceToDevice, stream);
  for (int i = 0; i < 5; ++i)
    hipMemcpyAsync(bias5 + i * 1024, bia[i], 4096, hipMemcpyDeviceToDevice, stream);

  // --- pipeline ---
  ushort* hb[2] = {h0, h1};
  int t = 0;
  for (int c = 0; c < 256 / chunk; ++c) {
    gemm_pre<<<dim3(chunk, 40), 256, 0, stream>>>(xb, xdb, Wb, bias5, P,
                                                  c * chunk, lc);
    for (int tt = 0; tt < chunk; ++tt, ++t)
      lstm_step<<<dim3(4, 64), 64, 0, stream>>>(hb[t & 1], hb[(t + 1) & 1], cbuf,
                                                Whb, P, hs, t, tt, lc);
  }
  gemm_post<<<dim3(256, 8), 256, 0, stream>>>(xb, hs, Wb + 5 * 524288,
                                              Whb + 3 * 1048576, Wrb, y);
  finish_kernel<<<512, 256, 0, stream>>>(h0, cbuf, y + 33554432);
}